// Round 7
// baseline (168.132 us; speedup 1.0000x reference)
//
#include <hip/hip_runtime.h>
#include <stdint.h>

#define M_DIM 2048
#define K_DIM 4096
#define N_DIM 11008

typedef int v4i __attribute__((ext_vector_type(4)));

// ---------------- workspace layout ----------------
#define WS_XQ_OFF   65536ull
#define WS_WT_OFF   8454144ull
#define WS_FULL_BYTES (8454144ull + 45088768ull)
#define WS_SMALL_BYTES 8454144ull

static __device__ __forceinline__ void llds16(const void* g, void* l) {
  __builtin_amdgcn_global_load_lds(
      reinterpret_cast<const uint32_t __attribute__((address_space(1)))*>(
          reinterpret_cast<uintptr_t>(g)),
      reinterpret_cast<uint32_t __attribute__((address_space(3)))*>(
          reinterpret_cast<uintptr_t>(l)),
      16, 0, 0);
}

// ---------------- kernel 1: per-block abs-max over x ----------------
__global__ __launch_bounds__(256) void absmax_kernel(const float* __restrict__ x,
                                                     float* __restrict__ part) {
  __shared__ float red[256];
  const int g = blockIdx.x * 256 + threadIdx.x;
  const float4* x4 = reinterpret_cast<const float4*>(x);
  float m = 0.f;
#pragma unroll
  for (int i = 0; i < 8; ++i) {
    float4 v = x4[(size_t)i * 262144 + g];
    m = fmaxf(m, fmaxf(fmaxf(fabsf(v.x), fabsf(v.y)),
                       fmaxf(fabsf(v.z), fabsf(v.w))));
  }
  red[threadIdx.x] = m;
  __syncthreads();
  for (int s = 128; s > 0; s >>= 1) {
    if (threadIdx.x < s) red[threadIdx.x] = fmaxf(red[threadIdx.x], red[threadIdx.x + s]);
    __syncthreads();
  }
  if (threadIdx.x == 0) part[blockIdx.x] = red[0];
}

// ---------------- kernel 2: finalize scales ----------------
__global__ __launch_bounds__(256) void finalize_scale(const float* __restrict__ part,
                                                      const float* __restrict__ y_scale,
                                                      float* __restrict__ scales) {
  __shared__ float red[256];
  const int t = threadIdx.x;
  float m = fmaxf(fmaxf(part[t], part[t + 256]), fmaxf(part[t + 512], part[t + 768]));
  red[t] = m;
  __syncthreads();
  for (int s = 128; s > 0; s >>= 1) {
    if (t < s) red[t] = fmaxf(red[t], red[t + s]);
    __syncthreads();
  }
  if (t == 0) {
    float xs = red[0] * (1.0f / 128.0f);  // exact (pow2)
    scales[0] = xs;
    scales[1] = xs * y_scale[0];
  }
}

// ---------------- kernel 3: quantize x -> int8 ----------------
__global__ __launch_bounds__(256) void quant_kernel(const float* __restrict__ x,
                                                    const float* __restrict__ scales,
                                                    signed char* __restrict__ xq) {
  const float s = scales[0];
  const size_t t = (size_t)blockIdx.x * 256 + threadIdx.x;
  const float4* x4 = reinterpret_cast<const float4*>(x) + t * 4;
  v4i o;
#pragma unroll
  for (int i = 0; i < 4; ++i) {
    float4 v = x4[i];
    int q0 = (int)rintf(v.x / s);  // matches np.round (half-to-even)
    int q1 = (int)rintf(v.y / s);
    int q2 = (int)rintf(v.z / s);
    int q3 = (int)rintf(v.w / s);
    q0 = max(-128, min(127, q0));
    q1 = max(-128, min(127, q1));
    q2 = max(-128, min(127, q2));
    q3 = max(-128, min(127, q3));
    o[i] = (q0 & 255) | ((q1 & 255) << 8) | ((q2 & 255) << 16) | ((q3 & 255) << 24);
  }
  *reinterpret_cast<v4i*>(xq + t * 16) = o;
}

// ---------------- kernel 4: transpose+pack w32[K,N] -> w_t int8[N,K] ----------------
__global__ __launch_bounds__(256) void transpose_pack(const int* __restrict__ w,
                                                      signed char* __restrict__ wt) {
  __shared__ int tile[64 * 65];
  const int t = threadIdx.x;
  const int n0 = blockIdx.x * 64;
  const int k0 = blockIdx.y * 64;
#pragma unroll
  for (int p = 0; p < 4; ++p) {
    const int id = p * 256 + t;
    const int r = id >> 4;
    const int c4 = id & 15;
    v4i v = *reinterpret_cast<const v4i*>(w + (size_t)(k0 + r) * N_DIM + n0 + c4 * 4);
    tile[r * 65 + c4 * 4 + 0] = v[0];
    tile[r * 65 + c4 * 4 + 1] = v[1];
    tile[r * 65 + c4 * 4 + 2] = v[2];
    tile[r * 65 + c4 * 4 + 3] = v[3];
  }
  __syncthreads();
  const int nl = t >> 2;
  const int kseg = t & 3;
  v4i o;
#pragma unroll
  for (int q = 0; q < 4; ++q) {
    const int kb = kseg * 16 + q * 4;
    int b0 = tile[(kb + 0) * 65 + nl] & 255;
    int b1 = tile[(kb + 1) * 65 + nl] & 255;
    int b2 = tile[(kb + 2) * 65 + nl] & 255;
    int b3 = tile[(kb + 3) * 65 + nl] & 255;
    o[q] = b0 | (b1 << 8) | (b2 << 16) | (b3 << 24);
  }
  *reinterpret_cast<v4i*>(wt + (size_t)(n0 + nl) * K_DIM + k0 + kseg * 16) = o;
}

// ---------------- kernel 5: int8 MFMA GEMM v7 (1 block/CU, 90% grid-eff) ------
// BM=128, BN=256, BK=128 bytes. 512 threads = 8 waves (2M x 4N), wave-tile
// 64x64 via 4x4 frags of mfma_i32_16x16x64_i8, 2 k-steps per K-tile.
// Ring-3 LDS = 3 x 48KB = 144KB -> exactly 1 block/CU: 688 blocks ->
// 2.69 rounds -> ~90% grid efficiency (vs 67% at 2 blk/CU with 688).
// R4/R6-proven single-phase body (trust-the-compiler): one vmcnt(6)+barrier
// per K-tile, no setprio / sched_barrier / lgkmcnt pins.
#define V7_BKB    128
#define V7_A_B    (128 * V7_BKB)            // 16 KB
#define V7_B_B    (256 * V7_BKB)            // 32 KB
#define V7_TILE_B (V7_A_B + V7_B_B)         // 48 KB
#define V7_NT     (K_DIM / V7_BKB)          // 32 K-tiles

__global__ __launch_bounds__(512, 2) void gemm_i8_v7(
    const signed char* __restrict__ xq, const signed char* __restrict__ wt,
    const float* __restrict__ scales, const float* __restrict__ bias,
    float* __restrict__ y) {
  __shared__ __align__(16) signed char smem[3 * V7_TILE_B];  // 144 KB
  const int tid = threadIdx.x;

  // T1: bijective XCD swizzle (688 blocks = 8 x 86), column-major grid
  // (16 m-tiles share each 1MB wt n-panel in L2).  [R2/R4/R6-proven]
  const int bid = blockIdx.x;
  const int swz = (bid & 7) * 86 + (bid >> 3);
  const int m0 = (swz & 15) * 128;
  const int n0 = (swz >> 4) * 256;

  // ---- staging map (R3 refcheck-proven, 0 conflicts): thread -> (row =
  // tid>>3, seg = tid&7) of a 128B row. LDS dest linear; XOR involution
  // seg' = seg ^ (row&7) on the GLOBAL source (both-sides rule). Row-block
  // offsets (+64,+128,+192) and k-offsets preserve row&7 -> invariant.
  const int srow = tid >> 3;   // 0..63
  const int sseg = tid & 7;
  const int sgoff = (sseg ^ (srow & 7)) * 16;
  const signed char* gA = xq + (size_t)(m0 + srow) * K_DIM + sgoff;
  const signed char* gB = wt + (size_t)(n0 + srow) * K_DIM + sgoff;
  signed char* const ld = smem + tid * 16;

#define STAGE(kt, soff)                                                     \
  do {                                                                      \
    const size_t ko_ = (size_t)(kt) * V7_BKB;                               \
    llds16(gA + ko_,                       ld + (soff));                    \
    llds16(gA + ko_ + (size_t)64 * K_DIM,  ld + (soff) + 8192);             \
    llds16(gB + ko_,                       ld + (soff) + V7_A_B);           \
    llds16(gB + ko_ + (size_t)64 * K_DIM,  ld + (soff) + V7_A_B + 8192);    \
    llds16(gB + ko_ + (size_t)128 * K_DIM, ld + (soff) + V7_A_B + 16384);   \
    llds16(gB + ko_ + (size_t)192 * K_DIM, ld + (soff) + V7_A_B + 24576);   \
  } while (0)

  // ---- fragment map (R3 refcheck-proven): lane l -> row l&15 (+16*frag),
  // 16B chunk kc = l>>4 within each 64B k-step; seg_phys = seg_log ^ (row&7);
  // frag row offsets are multiples of 16 -> swizzle depends on l15 only.
  const int lane = tid & 63;
  const int wid = tid >> 6;
  const int wm = wid >> 2;   // 0..1 -> 64-row half of the 128 rows
  const int wn = wid & 3;    // 0..3 -> 64-col quarter of the 256 cols
  const int l15 = lane & 15;
  const int kc = lane >> 4;
  const int sx0 = ((0 + kc) ^ (l15 & 7)) * 16;  // k-step 0 seg offset
  const int sx1 = ((4 + kc) ^ (l15 & 7)) * 16;  // k-step 1 seg offset
  const int offA = (wm * 64 + l15) * V7_BKB;            // + m*2048
  const int offB = V7_A_B + (wn * 64 + l15) * V7_BKB;   // + n*2048

  v4i acc[4][4] = {};

  // both k-steps, no barriers inside; two scoped sub-blocks so a_/b_
  // registers are reused across k-steps (VGPR <= 128 at (512,2)).
#define COMPUTE(roff)                                                        \
  do {                                                                       \
    const signed char* bp_ = smem + (roff);                                  \
    {                                                                        \
      v4i a_[4], b_[4];                                                      \
      _Pragma("unroll")                                                      \
      for (int m_ = 0; m_ < 4; ++m_)                                         \
        a_[m_] = *reinterpret_cast<const v4i*>(bp_ + offA + m_ * 2048 + sx0);\
      _Pragma("unroll")                                                      \
      for (int n_ = 0; n_ < 4; ++n_)                                         \
        b_[n_] = *reinterpret_cast<const v4i*>(bp_ + offB + n_ * 2048 + sx0);\
      _Pragma("unroll")                                                      \
      for (int m_ = 0; m_ < 4; ++m_)                                         \
        _Pragma("unroll")                                                    \
        for (int n_ = 0; n_ < 4; ++n_)                                       \
          acc[m_][n_] = __builtin_amdgcn_mfma_i32_16x16x64_i8(               \
              a_[m_], b_[n_], acc[m_][n_], 0, 0, 0);                         \
    }                                                                        \
    {                                                                        \
      v4i a_[4], b_[4];                                                      \
      _Pragma("unroll")                                                      \
      for (int m_ = 0; m_ < 4; ++m_)                                         \
        a_[m_] = *reinterpret_cast<const v4i*>(bp_ + offA + m_ * 2048 + sx1);\
      _Pragma("unroll")                                                      \
      for (int n_ = 0; n_ < 4; ++n_)                                         \
        b_[n_] = *reinterpret_cast<const v4i*>(bp_ + offB + n_ * 2048 + sx1);\
      _Pragma("unroll")                                                      \
      for (int m_ = 0; m_ < 4; ++m_)                                         \
        _Pragma("unroll")                                                    \
        for (int n_ = 0; n_ < 4; ++n_)                                       \
          acc[m_][n_] = __builtin_amdgcn_mfma_i32_16x16x64_i8(               \
              a_[m_], b_[n_], acc[m_][n_], 0, 0, 0);                         \
    }                                                                        \
  } while (0)

  // prologue: stage tiles 0,1 (12 loads/thread in flight); retire tile 0.
  STAGE(0, 0);
  STAGE(1, V7_TILE_B);
  asm volatile("s_waitcnt vmcnt(6)" ::: "memory");
  __builtin_amdgcn_s_barrier();

  int rOff = 0;
  int sOff = 2 * V7_TILE_B;
  for (int t = 0; t < V7_NT - 2; ++t) {
    STAGE(t + 2, sOff);              // outstanding: t+1:6, t+2:6
    COMPUTE(rOff);                   // 16 ds_read_b128 + 32 MFMA
    asm volatile("s_waitcnt vmcnt(6)" ::: "memory");  // retire tile t+1
    __builtin_amdgcn_s_barrier();
    rOff = (rOff == 2 * V7_TILE_B) ? 0 : rOff + V7_TILE_B;
    sOff = (sOff == 2 * V7_TILE_B) ? 0 : sOff + V7_TILE_B;
  }
  // t = NT-2: no staging; drain remaining tile
  COMPUTE(rOff);
  asm volatile("s_waitcnt vmcnt(0)" ::: "memory");
  __builtin_amdgcn_s_barrier();
  rOff = (rOff == 2 * V7_TILE_B) ? 0 : rOff + V7_TILE_B;
  // t = NT-1: final tile
  COMPUTE(rOff);

#undef STAGE
#undef COMPUTE

  // epilogue: C/D 16x16 layout col=lane&15, row=(lane>>4)*4+reg (R1-proven)
  const float s = scales[1];
#pragma unroll
  for (int n = 0; n < 4; ++n) {
    const int col = n0 + wn * 64 + n * 16 + l15;
    const float bv = bias[col];
#pragma unroll
    for (int m = 0; m < 4; ++m) {
      const int r0 = m0 + wm * 64 + m * 16 + kc * 4;
#pragma unroll
      for (int j = 0; j < 4; ++j)
        y[(size_t)(r0 + j) * N_DIM + col] = (float)acc[m][n][j] * s + bv;
    }
  }
}

// ---------------- fallback (small ws): sdot4 LDS GEMM reading w32 ----------------
#if defined(__has_builtin)
#if __has_builtin(__builtin_amdgcn_sdot4)
#define HAVE_SDOT4 1
#endif
#endif

static __device__ __forceinline__ int dot4(int a, int b, int c) {
#ifdef HAVE_SDOT4
  return __builtin_amdgcn_sdot4(a, b, c, false);
#else
  c += (int)(signed char)(a) * (int)(signed char)(b);
  c += (int)(signed char)(a >> 8) * (int)(signed char)(b >> 8);
  c += (int)(signed char)(a >> 16) * (int)(signed char)(b >> 16);
  c += (int)(signed char)(a >> 24) * (int)(signed char)(b >> 24);
  return c;
#endif
}

__global__ __launch_bounds__(256) void gemm_fallback(
    const signed char* __restrict__ xq, const int* __restrict__ w,
    const float* __restrict__ scales, const float* __restrict__ bias,
    float* __restrict__ y) {
  __shared__ int lds_a[64 * 17];
  __shared__ int lds_b[64 * 17];
  const int t = threadIdx.x;
  const int m0 = blockIdx.y * 64;
  const int n0 = blockIdx.x * 64;
  const int my = (t >> 4) * 4;
  const int nx = (t & 15) * 4;
  int acc[4][4] = {};
  for (int kt = 0; kt < K_DIM / 64; ++kt) {
    const int k0 = kt * 64;
    {
      const int r = t >> 2, sg = t & 3;
      v4i v = *reinterpret_cast<const v4i*>(xq + (size_t)(m0 + r) * K_DIM + k0 + sg * 16);
      lds_a[r * 17 + sg * 4 + 0] = v[0];
      lds_a[r * 17 + sg * 4 + 1] = v[1];
      lds_a[r * 17 + sg * 4 + 2] = v[2];
      lds_a[r * 17 + sg * 4 + 3] = v[3];
    }
    {
      const int n = t & 63, bkk = (t >> 6) * 4;
#pragma unroll
      for (int q = 0; q < 4; ++q) {
        const int kk = bkk + q;
        int b0 = w[(size_t)(k0 + kk * 4 + 0) * N_DIM + n0 + n] & 255;
        int b1 = w[(size_t)(k0 + kk * 4 + 1) * N_DIM + n0 + n] & 255;
        int b2 = w[(size_t)(k0 + kk * 4 + 2) * N_DIM + n0 + n] & 255;
        int b3 = w[(size_t)(k0 + kk * 4 + 3) * N_DIM + n0 + n] & 255;
        lds_b[n * 17 + kk] = b0 | (b1 << 8) | (b2 << 16) | (b3 << 24);
      }
    }
    __syncthreads();
#pragma unroll
    for (int kk = 0; kk < 16; ++kk) {
      int a[4], b[4];
#pragma unroll
      for (int i = 0; i < 4; ++i) a[i] = lds_a[(my + i) * 17 + kk];
#pragma unroll
      for (int j = 0; j < 4; ++j) b[j] = lds_b[(nx + j) * 17 + kk];
#pragma unroll
      for (int i = 0; i < 4; ++i)
#pragma unroll
        for (int j = 0; j < 4; ++j) acc[i][j] = dot4(a[i], b[j], acc[i][j]);
    }
    __syncthreads();
  }
  const float s = scales[1];
#pragma unroll
  for (int i = 0; i < 4; ++i)
#pragma unroll
    for (int j = 0; j < 4; ++j)
      y[(size_t)(m0 + my + i) * N_DIM + n0 + nx + j] =
          (float)acc[i][j] * s + bias[n0 + nx + j];
}

// ---------------- launcher ----------------
extern "C" void kernel_launch(void* const* d_in, const int* in_sizes, int n_in,
                              void* d_out, int out_size, void* d_ws, size_t ws_size,
                              hipStream_t stream) {
  (void)in_sizes; (void)n_in; (void)out_size;
  const float* x = (const float*)d_in[0];
  const int* w = (const int*)d_in[1];  // int8 values stored as int32
  const float* bias = (const float*)d_in[2];
  const float* yscale = (const float*)d_in[3];
  float* y = (float*)d_out;
  char* ws = (char*)d_ws;
  float* scales = (float*)(ws);
  float* part = (float*)(ws + 1024);
  signed char* xq = (signed char*)(ws + WS_XQ_OFF);
  signed char* wt = (signed char*)(ws + WS_WT_OFF);

  if (ws_size < WS_SMALL_BYTES) return;

  absmax_kernel<<<1024, 256, 0, stream>>>(x, part);
  finalize_scale<<<1, 256, 0, stream>>>(part, yscale, scales);
  quant_kernel<<<2048, 256, 0, stream>>>(x, scales, xq);
  if (ws_size >= WS_FULL_BYTES) {
    transpose_pack<<<dim3(N_DIM / 64, K_DIM / 64), 256, 0, stream>>>(w, wt);
    gemm_i8_v7<<<(M_DIM / 128) * (N_DIM / 256), 512, 0, stream>>>(xq, wt, scales, bias, y);
  } else {
    gemm_fallback<<<dim3(N_DIM / 64, M_DIM / 64), 256, 0, stream>>>(xq, w, scales, bias, y);
  }
}

// Round 8
// 158.592 us; speedup vs baseline: 1.0602x; 1.0602x over previous
//
#include <hip/hip_runtime.h>
#include <stdint.h>

#define M_DIM 2048
#define K_DIM 4096
#define N_DIM 11008

typedef int v4i  __attribute__((ext_vector_type(4)));
typedef int v16i __attribute__((ext_vector_type(16)));

// ---------------- workspace layout ----------------
// xq_packed: [mblk=16][kt=64][u=512]x16B  (8 MB)  fragment-ordered, see below
// wt_packed: [nblk=43][kt=64][u=1024]x16B (45 MB)
#define WS_XQ_OFF   65536ull
#define WS_WT_OFF   8454144ull
#define WS_FULL_BYTES (8454144ull + 45088768ull)
#define WS_SMALL_BYTES 8454144ull

static __device__ __forceinline__ void llds16(const void* g, void* l) {
  __builtin_amdgcn_global_load_lds(
      reinterpret_cast<const uint32_t __attribute__((address_space(1)))*>(
          reinterpret_cast<uintptr_t>(g)),
      reinterpret_cast<uint32_t __attribute__((address_space(3)))*>(
          reinterpret_cast<uintptr_t>(l)),
      16, 0, 0);
}

// ---------------- kernel 1: per-block abs-max over x ----------------
__global__ __launch_bounds__(256) void absmax_kernel(const float* __restrict__ x,
                                                     float* __restrict__ part) {
  __shared__ float red[256];
  const int g = blockIdx.x * 256 + threadIdx.x;
  const float4* x4 = reinterpret_cast<const float4*>(x);
  float m = 0.f;
#pragma unroll
  for (int i = 0; i < 8; ++i) {
    float4 v = x4[(size_t)i * 262144 + g];
    m = fmaxf(m, fmaxf(fmaxf(fabsf(v.x), fabsf(v.y)),
                       fmaxf(fabsf(v.z), fabsf(v.w))));
  }
  red[threadIdx.x] = m;
  __syncthreads();
  for (int s = 128; s > 0; s >>= 1) {
    if (threadIdx.x < s) red[threadIdx.x] = fmaxf(red[threadIdx.x], red[threadIdx.x + s]);
    __syncthreads();
  }
  if (threadIdx.x == 0) part[blockIdx.x] = red[0];
}

// ---------------- kernel 2: finalize scales ----------------
__global__ __launch_bounds__(256) void finalize_scale(const float* __restrict__ part,
                                                      const float* __restrict__ y_scale,
                                                      float* __restrict__ scales) {
  __shared__ float red[256];
  const int t = threadIdx.x;
  float m = fmaxf(fmaxf(part[t], part[t + 256]), fmaxf(part[t + 512], part[t + 768]));
  red[t] = m;
  __syncthreads();
  for (int s = 128; s > 0; s >>= 1) {
    if (t < s) red[t] = fmaxf(red[t], red[t + s]);
    __syncthreads();
  }
  if (t == 0) {
    float xs = red[0] * (1.0f / 128.0f);  // exact (pow2)
    scales[0] = xs;
    scales[1] = xs * y_scale[0];
  }
}

static __device__ __forceinline__ int quant4(float4 v, float s) {
  int q0 = (int)rintf(v.x / s);  // matches np.round (half-to-even)
  int q1 = (int)rintf(v.y / s);
  int q2 = (int)rintf(v.z / s);
  int q3 = (int)rintf(v.w / s);
  q0 = max(-128, min(127, q0));
  q1 = max(-128, min(127, q1));
  q2 = max(-128, min(127, q2));
  q3 = max(-128, min(127, q3));
  return (q0 & 255) | ((q1 & 255) << 8) | ((q2 & 255) << 16) | ((q3 & 255) << 24);
}

// ---------------- kernel 3a: quantize x -> xq_packed (fragment order) --------
// Unit u (16B) within [mblk][kt]: u = (rowgrp<<7)|(kstep<<6)|(khalf<<5)|row32.
// Holds x[mblk*128 + rowgrp*32 + row32][kt*64 + kstep*32 + khalf*16 .. +15].
// Writes perfectly linear; reads: lane pairs (l, l^32) share one 128B line.
__global__ __launch_bounds__(256) void quant_pack(const float* __restrict__ x,
                                                  const float* __restrict__ scales,
                                                  signed char* __restrict__ xq) {
  const float s = scales[0];
  const int g = blockIdx.x * 256 + threadIdx.x;   // unit id, 524288 total
  const int mblk = g >> 15;
  const int kt = (g >> 9) & 63;
  const int u = g & 511;
  const int row = mblk * 128 + ((u >> 7) & 3) * 32 + (u & 31);
  const int kf = kt * 64 + ((u >> 6) & 1) * 32 + ((u >> 5) & 1) * 16;
  const float4* xp = reinterpret_cast<const float4*>(x + (size_t)row * K_DIM + kf);
  v4i o;
#pragma unroll
  for (int i = 0; i < 4; ++i) o[i] = quant4(xp[i], s);
  *reinterpret_cast<v4i*>(xq + (size_t)g * 16) = o;
}

// ---------------- kernel 3b: row-major quant (fallback path only) ------------
__global__ __launch_bounds__(256) void quant_rowmajor(const float* __restrict__ x,
                                                      const float* __restrict__ scales,
                                                      signed char* __restrict__ xq) {
  const float s = scales[0];
  const size_t t = (size_t)blockIdx.x * 256 + threadIdx.x;
  const float4* x4 = reinterpret_cast<const float4*>(x) + t * 4;
  v4i o;
#pragma unroll
  for (int i = 0; i < 4; ++i) o[i] = quant4(x4[i], s);
  *reinterpret_cast<v4i*>(xq + t * 16) = o;
}

// ---------------- kernel 4: transpose+pack w32[K,N] -> wt_packed --------------
// Unit u within [nblk][kt]: u = (ngrp<<7)|(kstep<<6)|(khalf<<5)|n32.
// Holds w[kt*64 + kstep*32 + khalf*16 .. +15][nblk*256 + ngrp*32 + n32] (int8).
// Block = 64 n-cols x 64 k-rows; thread t emits unit (ngrp_base<<7)+t.
__global__ __launch_bounds__(256) void transpose_pack(const int* __restrict__ w,
                                                      signed char* __restrict__ wt) {
  __shared__ int tile[64 * 65];  // [k][n], pad 65
  const int t = threadIdx.x;
  const int bx = blockIdx.x;          // n-tile (64 cols)
  const int by = blockIdx.y;          // k-tile (64 rows)
  const int n0 = bx * 64;
  const int k0 = by * 64;
#pragma unroll
  for (int p = 0; p < 4; ++p) {
    const int id = p * 256 + t;
    const int r = id >> 4;
    const int c4 = id & 15;
    v4i v = *reinterpret_cast<const v4i*>(w + (size_t)(k0 + r) * N_DIM + n0 + c4 * 4);
    tile[r * 65 + c4 * 4 + 0] = v[0];
    tile[r * 65 + c4 * 4 + 1] = v[1];
    tile[r * 65 + c4 * 4 + 2] = v[2];
    tile[r * 65 + c4 * 4 + 3] = v[3];
  }
  __syncthreads();
  // thread t -> unit: nl = (t>>7)*32 + (t&31)  (0..63), kc = (t>>5)&3
  const int nl = ((t >> 7) << 5) | (t & 31);
  const int kc = (t >> 5) & 3;
  v4i o;
#pragma unroll
  for (int q = 0; q < 4; ++q) {
    const int kb = kc * 16 + q * 4;
    int b0 = tile[(kb + 0) * 65 + nl] & 255;
    int b1 = tile[(kb + 1) * 65 + nl] & 255;
    int b2 = tile[(kb + 2) * 65 + nl] & 255;
    int b3 = tile[(kb + 3) * 65 + nl] & 255;
    o[q] = b0 | (b1 << 8) | (b2 << 16) | (b3 << 24);
  }
  const size_t base = ((size_t)(bx >> 2) * 64 + by) * 16384;   // [nblk][kt]
  const int ubase = ((bx & 3) * 2) << 7;                        // ngrp_base*128
  *reinterpret_cast<v4i*>(wt + base + (size_t)(ubase + t) * 16) = o;
}

// ---------------- kernel 5: int8 MFMA GEMM v8 (32x32x32, packed operands) -----
// BM=128, BN=256, BK=64 bytes. 512 threads = 8 waves (2M x 4N), wave-tile
// 64x64 via 2x2 frags of mfma_i32_32x32x32_i8 (half the instrs of 16x16x64
// at equal work). Operands pre-packed in fragment order: staging is 3
// contiguous global_load_lds / thread; all ds_read_b128 are base + lane*16
// (canonical conflict-free). Ring-3 x 24KB = 72KB -> 2 blk/CU (R4-proven).
// Depth-2 prefetch, vmcnt(3) once per K-tile (never 0 in main loop).
#define V8_TILE_B 24576           // A 8KB + B 16KB
#define V8_NT     (K_DIM / 64)    // 64 K-tiles

__global__ __launch_bounds__(512, 4) void gemm_i8_v8(
    const signed char* __restrict__ xq, const signed char* __restrict__ wt,
    const float* __restrict__ scales, const float* __restrict__ bias,
    float* __restrict__ y) {
  __shared__ __align__(16) signed char smem[3 * V8_TILE_B];  // 72 KB
  const int tid = threadIdx.x;

  // T1: bijective XCD swizzle (688 blocks = 8 x 86), column-major grid.
  const int bid = blockIdx.x;
  const int swz = (bid & 7) * 86 + (bid >> 3);
  const int mblk = swz & 15;        // 16 m-tiles of 128
  const int nblk = swz >> 4;        // 43 n-tiles of 256
  const int m0 = mblk * 128;
  const int n0 = nblk * 256;

  // staging: fragment-packed global source, contiguous per (blk, kt).
  const signed char* gA = xq + (size_t)mblk * 64 * 8192;    // + kt*8192  + tid*16
  const signed char* gB = wt + (size_t)nblk * 64 * 16384;   // + kt*16384 + tid*16 (+8192)
  signed char* const ld = smem + tid * 16;

#define STAGE(kt, soff)                                                   \
  do {                                                                    \
    llds16(gA + (size_t)(kt) * 8192 + tid * 16,         ld + (soff));     \
    llds16(gB + (size_t)(kt) * 16384 + tid * 16,        ld + (soff) + 8192);  \
    llds16(gB + (size_t)(kt) * 16384 + 8192 + tid * 16, ld + (soff) + 16384); \
  } while (0)

  // fragment map: LDS image is unit-ordered; frag (grp, kstep) lives at
  // grp*2048 + kstep*1024 + lane*16  (A: grp = wm*2+fa in [0,4); B: wn*2+fb in [0,8)).
  const int lane = tid & 63;
  const int wid = tid >> 6;
  const int wm = wid >> 2;   // 0..1
  const int wn = wid & 3;    // 0..3
  const int aoff = (wm * 2) * 2048 + lane * 16;           // + fa*2048 + ks*1024
  const int boff = 8192 + (wn * 2) * 2048 + lane * 16;    // + fb*2048 + ks*1024

  v16i acc[2][2] = {};

#define COMPUTE(roff)                                                         \
  do {                                                                        \
    const signed char* bp_ = smem + (roff);                                   \
    _Pragma("unroll")                                                         \
    for (int ks_ = 0; ks_ < 2; ++ks_) {                                       \
      v4i a0 = *reinterpret_cast<const v4i*>(bp_ + aoff + ks_ * 1024);        \
      v4i a1 = *reinterpret_cast<const v4i*>(bp_ + aoff + 2048 + ks_ * 1024); \
      v4i b0 = *reinterpret_cast<const v4i*>(bp_ + boff + ks_ * 1024);        \
      v4i b1 = *reinterpret_cast<const v4i*>(bp_ + boff + 2048 + ks_ * 1024); \
      acc[0][0] = __builtin_amdgcn_mfma_i32_32x32x32_i8(a0, b0, acc[0][0], 0, 0, 0); \
      acc[0][1] = __builtin_amdgcn_mfma_i32_32x32x32_i8(a0, b1, acc[0][1], 0, 0, 0); \
      acc[1][0] = __builtin_amdgcn_mfma_i32_32x32x32_i8(a1, b0, acc[1][0], 0, 0, 0); \
      acc[1][1] = __builtin_amdgcn_mfma_i32_32x32x32_i8(a1, b1, acc[1][1], 0, 0, 0); \
    }                                                                         \
  } while (0)

  // prologue: stage tiles 0,1 (6 loads/thread in flight); retire tile 0.
  STAGE(0, 0);
  STAGE(1, V8_TILE_B);
  asm volatile("s_waitcnt vmcnt(3)" ::: "memory");
  __builtin_amdgcn_s_barrier();

  int rOff = 0;
  int sOff = 2 * V8_TILE_B;
  for (int t = 0; t < V8_NT - 2; ++t) {
    STAGE(t + 2, sOff);              // outstanding: t+1:3, t+2:3
    COMPUTE(rOff);                   // 8 ds_read_b128 + 8 MFMA (32x32x32)
    asm volatile("s_waitcnt vmcnt(3)" ::: "memory");  // retire tile t+1
    __builtin_amdgcn_s_barrier();
    rOff = (rOff == 2 * V8_TILE_B) ? 0 : rOff + V8_TILE_B;
    sOff = (sOff == 2 * V8_TILE_B) ? 0 : sOff + V8_TILE_B;
  }
  // t = NT-2: no staging; drain remaining tile
  COMPUTE(rOff);
  asm volatile("s_waitcnt vmcnt(0)" ::: "memory");
  __builtin_amdgcn_s_barrier();
  rOff = (rOff == 2 * V8_TILE_B) ? 0 : rOff + V8_TILE_B;
  // t = NT-1: final tile
  COMPUTE(rOff);

#undef STAGE
#undef COMPUTE

  // epilogue: 32x32 C/D layout col=lane&31, row=(reg&3)+8*(reg>>2)+4*(lane>>5)
  // [measured: m74/m101, dtype-independent]
  const float s = scales[1];
  const int l31 = lane & 31;
  const int lh4 = (lane >> 5) * 4;
#pragma unroll
  for (int fb = 0; fb < 2; ++fb) {
    const int col = n0 + wn * 64 + fb * 32 + l31;
    const float bv = bias[col];
#pragma unroll
    for (int fa = 0; fa < 2; ++fa) {
      const int rbase = m0 + wm * 64 + fa * 32 + lh4;
#pragma unroll
      for (int reg = 0; reg < 16; ++reg) {
        const int row = rbase + (reg & 3) + 8 * (reg >> 2);
        y[(size_t)row * N_DIM + col] = (float)acc[fa][fb][reg] * s + bv;
      }
    }
  }
}

// ---------------- fallback (small ws): sdot4 LDS GEMM reading w32 ----------------
#if defined(__has_builtin)
#if __has_builtin(__builtin_amdgcn_sdot4)
#define HAVE_SDOT4 1
#endif
#endif

static __device__ __forceinline__ int dot4(int a, int b, int c) {
#ifdef HAVE_SDOT4
  return __builtin_amdgcn_sdot4(a, b, c, false);
#else
  c += (int)(signed char)(a) * (int)(signed char)(b);
  c += (int)(signed char)(a >> 8) * (int)(signed char)(b >> 8);
  c += (int)(signed char)(a >> 16) * (int)(signed char)(b >> 16);
  c += (int)(signed char)(a >> 24) * (int)(signed char)(b >> 24);
  return c;
#endif
}

__global__ __launch_bounds__(256) void gemm_fallback(
    const signed char* __restrict__ xq, const int* __restrict__ w,
    const float* __restrict__ scales, const float* __restrict__ bias,
    float* __restrict__ y) {
  __shared__ int lds_a[64 * 17];
  __shared__ int lds_b[64 * 17];
  const int t = threadIdx.x;
  const int m0 = blockIdx.y * 64;
  const int n0 = blockIdx.x * 64;
  const int my = (t >> 4) * 4;
  const int nx = (t & 15) * 4;
  int acc[4][4] = {};
  for (int kt = 0; kt < K_DIM / 64; ++kt) {
    const int k0 = kt * 64;
    {
      const int r = t >> 2, sg = t & 3;
      v4i v = *reinterpret_cast<const v4i*>(xq + (size_t)(m0 + r) * K_DIM + k0 + sg * 16);
      lds_a[r * 17 + sg * 4 + 0] = v[0];
      lds_a[r * 17 + sg * 4 + 1] = v[1];
      lds_a[r * 17 + sg * 4 + 2] = v[2];
      lds_a[r * 17 + sg * 4 + 3] = v[3];
    }
    {
      const int n = t & 63, bkk = (t >> 6) * 4;
#pragma unroll
      for (int q = 0; q < 4; ++q) {
        const int kk = bkk + q;
        int b0 = w[(size_t)(k0 + kk * 4 + 0) * N_DIM + n0 + n] & 255;
        int b1 = w[(size_t)(k0 + kk * 4 + 1) * N_DIM + n0 + n] & 255;
        int b2 = w[(size_t)(k0 + kk * 4 + 2) * N_DIM + n0 + n] & 255;
        int b3 = w[(size_t)(k0 + kk * 4 + 3) * N_DIM + n0 + n] & 255;
        lds_b[n * 17 + kk] = b0 | (b1 << 8) | (b2 << 16) | (b3 << 24);
      }
    }
    __syncthreads();
#pragma unroll
    for (int kk = 0; kk < 16; ++kk) {
      int a[4], b[4];
#pragma unroll
      for (int i = 0; i < 4; ++i) a[i] = lds_a[(my + i) * 17 + kk];
#pragma unroll
      for (int j = 0; j < 4; ++j) b[j] = lds_b[(nx + j) * 17 + kk];
#pragma unroll
      for (int i = 0; i < 4; ++i)
#pragma unroll
        for (int j = 0; j < 4; ++j) acc[i][j] = dot4(a[i], b[j], acc[i][j]);
    }
    __syncthreads();
  }
  const float s = scales[1];
#pragma unroll
  for (int i = 0; i < 4; ++i)
#pragma unroll
    for (int j = 0; j < 4; ++j)
      y[(size_t)(m0 + my + i) * N_DIM + n0 + nx + j] =
          (float)acc[i][j] * s + bias[n0 + nx + j];
}

// ---------------- launcher ----------------
extern "C" void kernel_launch(void* const* d_in, const int* in_sizes, int n_in,
                              void* d_out, int out_size, void* d_ws, size_t ws_size,
                              hipStream_t stream) {
  (void)in_sizes; (void)n_in; (void)out_size;
  const float* x = (const float*)d_in[0];
  const int* w = (const int*)d_in[1];  // int8 values stored as int32
  const float* bias = (const float*)d_in[2];
  const float* yscale = (const float*)d_in[3];
  float* y = (float*)d_out;
  char* ws = (char*)d_ws;
  float* scales = (float*)(ws);
  float* part = (float*)(ws + 1024);
  signed char* xq = (signed char*)(ws + WS_XQ_OFF);
  signed char* wt = (signed char*)(ws + WS_WT_OFF);

  if (ws_size < WS_SMALL_BYTES) return;

  absmax_kernel<<<1024, 256, 0, stream>>>(x, part);
  finalize_scale<<<1, 256, 0, stream>>>(part, yscale, scales);
  if (ws_size >= WS_FULL_BYTES) {
    quant_pack<<<2048, 256, 0, stream>>>(x, scales, xq);
    transpose_pack<<<dim3(N_DIM / 64, K_DIM / 64), 256, 0, stream>>>(w, wt);
    gemm_i8_v8<<<(M_DIM / 128) * (N_DIM / 256), 512, 0, stream>>>(xq, wt, scales, bias, y);
  } else {
    quant_rowmajor<<<2048, 256, 0, stream>>>(x, scales, xq);
    gemm_fallback<<<dim3(N_DIM / 64, M_DIM / 64), 256, 0, stream>>>(xq, w, scales, bias, y);
  }
}